// Round 4
// baseline (137.537 us; speedup 1.0000x reference)
//
#include <hip/hip_runtime.h>
#include <math.h>

#define LSEQ 4096
#define DD 768
#define NST 16
#define RNK 48
#define TCH 32
#define NCH (LSEQ / TCH)   // 128 chunks
#define LTILE 8

__device__ __forceinline__ float softplus_f(float z) {
    return fmaxf(z, 0.0f) + log1pf(expf(-fabsf(z)));
}

__device__ __forceinline__ float soft_clamp_f(float v) {
    const float ctr = 5.00005f;
    const float hr  = 4.99995f;
    const float inv_hr = 1.0f / 4.99995f;
    return ctr + hr * tanhf((v - ctr) * inv_hr);
}

__device__ __forceinline__ float wave_sum(float v) {
    #pragma unroll
    for (int m = 32; m >= 1; m >>= 1) v += __shfl_xor(v, m, 64);
    return v;
}

// ---------------------------------------------------------------------------
// Kernel 1: per 8-timestep tile, compute
//   t  = x @ W_dt            (8 x 48)
//   bc = x @ W_bc            (8 x 32)  -> stored to global
//   delta = soft_clamp(rmsnorm(softplus(t @ W_dtp + b_dt)) * rms_scale)
// ---------------------------------------------------------------------------
__global__ __launch_bounds__(512) void k_proj(
    const float* __restrict__ x, const float* __restrict__ W_bc,
    const float* __restrict__ W_dt, const float* __restrict__ W_dtp,
    const float* __restrict__ b_dt, const float* __restrict__ rms_scale,
    float* __restrict__ delta_out, float* __restrict__ bc_out)
{
    __shared__ float x_lds[LTILE][DD];          // 24 KB
    __shared__ float t_lds[LTILE][RNK];         // 1.5 KB
    __shared__ float red[6][LTILE][80];         // 15 KB
    __shared__ float red2[8];
    __shared__ float s_inv;

    const int tid = threadIdx.x;
    const int l0  = blockIdx.x * LTILE;

    for (int i = tid; i < LTILE * DD; i += 512) {
        int li = i / DD, d = i % DD;
        x_lds[li][d] = x[(size_t)(l0 + li) * DD + d];
    }
    __syncthreads();

    // ---- phase A: t (48 cols) and bc (32 cols), split-K over 6 partials ----
    {
        const int j = tid % 80, p = tid / 80;   // p in 0..6, p==6 idle
        if (p < 6) {
            float acc[LTILE];
            #pragma unroll
            for (int li = 0; li < LTILE; ++li) acc[li] = 0.f;
            const int dbase = p * 128;
            if (j < RNK) {
                for (int i = 0; i < 128; ++i) {
                    int d = dbase + i;
                    float w = W_dt[d * RNK + j];
                    #pragma unroll
                    for (int li = 0; li < LTILE; ++li)
                        acc[li] = fmaf(x_lds[li][d], w, acc[li]);
                }
            } else {
                int jb = j - RNK;
                for (int i = 0; i < 128; ++i) {
                    int d = dbase + i;
                    float w = W_bc[d * 32 + jb];
                    #pragma unroll
                    for (int li = 0; li < LTILE; ++li)
                        acc[li] = fmaf(x_lds[li][d], w, acc[li]);
                }
            }
            #pragma unroll
            for (int li = 0; li < LTILE; ++li) red[p][li][j] = acc[li];
        }
    }
    __syncthreads();
    for (int idx = tid; idx < LTILE * 80; idx += 512) {
        int li = idx / 80, jj = idx % 80;
        float s = red[0][li][jj] + red[1][li][jj] + red[2][li][jj]
                + red[3][li][jj] + red[4][li][jj] + red[5][li][jj];
        if (jj < RNK) t_lds[li][jj] = s;
        else          bc_out[(size_t)(l0 + li) * 32 + (jj - RNK)] = s;
    }
    __syncthreads();

    // ---- phase B: delta = soft_clamp(rmsnorm(softplus(t @ W_dtp + b))) ----
    const int d0 = tid;                 // 0..511
    const int d1 = tid + 512;           // valid if tid < 256
    const bool has2 = (tid < 256);

    float z0[LTILE], z1[LTILE];
    float bb0 = b_dt[d0];
    float rs0 = rms_scale[d0];
    float bb1 = has2 ? b_dt[d1] : 0.f;
    float rs1 = has2 ? rms_scale[d1] : 0.f;
    #pragma unroll
    for (int li = 0; li < LTILE; ++li) { z0[li] = bb0; z1[li] = bb1; }

    for (int r = 0; r < RNK; ++r) {
        float w0 = W_dtp[r * DD + d0];
        float w1 = has2 ? W_dtp[r * DD + d1] : 0.f;
        #pragma unroll
        for (int li = 0; li < LTILE; ++li) {
            float t = t_lds[li][r];
            z0[li] = fmaf(t, w0, z0[li]);
            z1[li] = fmaf(t, w1, z1[li]);
        }
    }
    float sp0[LTILE], sp1[LTILE];
    #pragma unroll
    for (int li = 0; li < LTILE; ++li) {
        sp0[li] = softplus_f(z0[li]);
        sp1[li] = has2 ? softplus_f(z1[li]) : 0.f;
    }

    const int wid = tid >> 6, lane = tid & 63;
    for (int li = 0; li < LTILE; ++li) {
        float ss = sp0[li] * sp0[li] + sp1[li] * sp1[li];
        float w = wave_sum(ss);
        if (lane == 0) red2[wid] = w;
        __syncthreads();
        if (tid == 0) {
            float tot = 0.f;
            #pragma unroll
            for (int k = 0; k < 8; ++k) tot += red2[k];
            s_inv = rsqrtf(tot * (1.0f / DD) + 1e-6f);
        }
        __syncthreads();
        float inv = s_inv;
        float dl0 = soft_clamp_f(sp0[li] * inv * rs0);
        delta_out[(size_t)(l0 + li) * DD + d0] = dl0;
        if (has2) {
            float dl1 = soft_clamp_f(sp1[li] * inv * rs1);
            delta_out[(size_t)(l0 + li) * DD + d1] = dl1;
        }
        __syncthreads();
    }
}

// ---------------------------------------------------------------------------
// Scan pass 1: per (d, chunk) compute local scan with h=0; store prod(a), h_end
// layout of Pbuf/Hbuf: [(c*16+n)*768 + d]
// ---------------------------------------------------------------------------
__global__ __launch_bounds__(256) void k_scan1(
    const float* __restrict__ x, const float* __restrict__ delta,
    const float* __restrict__ bc, const float* __restrict__ A_log,
    float* __restrict__ Pbuf, float* __restrict__ Hbuf)
{
    const int d = blockIdx.x * 256 + threadIdx.x;
    const int c = blockIdx.y;
    const int l0 = c * TCH;

    float An[NST];
    #pragma unroll
    for (int n = 0; n < NST; ++n) An[n] = -expf(A_log[d * NST + n]);
    float h[NST], Pp[NST];
    #pragma unroll
    for (int n = 0; n < NST; ++n) { h[n] = 0.f; Pp[n] = 1.f; }

    float xprev = (l0 == 0) ? 0.f : x[(size_t)(l0 - 1) * DD + d];
    float dv = delta[(size_t)l0 * DD + d];
    float xv = x[(size_t)l0 * DD + d];
    const float4* bcv = (const float4*)bc;
    float4 b0 = bcv[l0 * 8 + 0], b1 = bcv[l0 * 8 + 1],
           b2 = bcv[l0 * 8 + 2], b3 = bcv[l0 * 8 + 3];

    for (int ll = 0; ll < TCH; ++ll) {
        const int l = l0 + ll;
        const int lnx = (l + 1 < LSEQ) ? l + 1 : l;
        float dv_c = dv, xv_c = xv;
        float4 c0v = b0, c1v = b1, c2v = b2, c3v = b3;
        dv = delta[(size_t)lnx * DD + d];
        xv = x[(size_t)lnx * DD + d];
        b0 = bcv[lnx * 8 + 0]; b1 = bcv[lnx * 8 + 1];
        b2 = bcv[lnx * 8 + 2]; b3 = bcv[lnx * 8 + 3];

        float xin = 0.5f * (xv_c + xprev);
        xprev = xv_c;
        float c0 = 0.5f * dv_c;
        float c1 = sqrtf(dv_c) * xin;
        float Bs[NST] = {c0v.x, c0v.y, c0v.z, c0v.w, c1v.x, c1v.y, c1v.z, c1v.w,
                         c2v.x, c2v.y, c2v.z, c2v.w, c3v.x, c3v.y, c3v.z, c3v.w};
        #pragma unroll
        for (int n = 0; n < NST; ++n) {
            float denom = fmaf(-c0, An[n], 1.0f);       // 1 - 0.5*delta*A
            float inv = __builtin_amdgcn_rcpf(denom);
            float a = (2.0f - denom) * inv;             // (1+half)/(1-half)
            Pp[n] *= a;
            h[n] = fmaf(a, h[n], c1 * Bs[n] * inv);
        }
    }
    #pragma unroll
    for (int n = 0; n < NST; ++n) {
        int idx = (c * NST + n) * DD + d;
        Pbuf[idx] = Pp[n];
        Hbuf[idx] = h[n];
    }
}

// ---------------------------------------------------------------------------
// Scan pass 2: per (d,n), sequential carry over 128 chunks.
// Overwrites Pbuf[idx] with carry-IN of that chunk.
// ---------------------------------------------------------------------------
__global__ __launch_bounds__(256) void k_scan2(
    float* __restrict__ Pbuf, const float* __restrict__ Hbuf)
{
    const int t = blockIdx.x * 256 + threadIdx.x;   // 0..12287
    const int d = t % DD;
    const int n = t / DD;
    const int stride = NST * DD;
    int idx = n * DD + d;
    float carry = 0.f;
    #pragma unroll 4
    for (int c = 0; c < NCH; ++c) {
        float p = Pbuf[idx], h = Hbuf[idx];
        Pbuf[idx] = carry;
        carry = fmaf(p, carry, h);
        idx += stride;
    }
}

// ---------------------------------------------------------------------------
// Scan pass 3: redo local scan seeded with carry-in; emit y = sum_n C*h + D*x
// ---------------------------------------------------------------------------
__global__ __launch_bounds__(256) void k_scan3(
    const float* __restrict__ x, const float* __restrict__ delta,
    const float* __restrict__ bc, const float* __restrict__ A_log,
    const float* __restrict__ carryin, const float* __restrict__ D_param,
    float* __restrict__ out)
{
    const int d = blockIdx.x * 256 + threadIdx.x;
    const int c = blockIdx.y;
    const int l0 = c * TCH;

    float An[NST];
    #pragma unroll
    for (int n = 0; n < NST; ++n) An[n] = -expf(A_log[d * NST + n]);
    float h[NST];
    #pragma unroll
    for (int n = 0; n < NST; ++n) h[n] = carryin[(c * NST + n) * DD + d];
    const float Dp = D_param[d];

    float xprev = (l0 == 0) ? 0.f : x[(size_t)(l0 - 1) * DD + d];
    float dv = delta[(size_t)l0 * DD + d];
    float xv = x[(size_t)l0 * DD + d];
    const float4* bcv = (const float4*)bc;
    float4 b0 = bcv[l0 * 8 + 0], b1 = bcv[l0 * 8 + 1],
           b2 = bcv[l0 * 8 + 2], b3 = bcv[l0 * 8 + 3],
           b4 = bcv[l0 * 8 + 4], b5 = bcv[l0 * 8 + 5],
           b6 = bcv[l0 * 8 + 6], b7 = bcv[l0 * 8 + 7];

    for (int ll = 0; ll < TCH; ++ll) {
        const int l = l0 + ll;
        const int lnx = (l + 1 < LSEQ) ? l + 1 : l;
        float dv_c = dv, xv_c = xv;
        float4 c0v = b0, c1v = b1, c2v = b2, c3v = b3;
        float4 c4v = b4, c5v = b5, c6v = b6, c7v = b7;
        dv = delta[(size_t)lnx * DD + d];
        xv = x[(size_t)lnx * DD + d];
        b0 = bcv[lnx * 8 + 0]; b1 = bcv[lnx * 8 + 1];
        b2 = bcv[lnx * 8 + 2]; b3 = bcv[lnx * 8 + 3];
        b4 = bcv[lnx * 8 + 4]; b5 = bcv[lnx * 8 + 5];
        b6 = bcv[lnx * 8 + 6]; b7 = bcv[lnx * 8 + 7];

        float xin = 0.5f * (xv_c + xprev);
        xprev = xv_c;
        float c0 = 0.5f * dv_c;
        float c1 = sqrtf(dv_c) * xin;
        float Bs[NST] = {c0v.x, c0v.y, c0v.z, c0v.w, c1v.x, c1v.y, c1v.z, c1v.w,
                         c2v.x, c2v.y, c2v.z, c2v.w, c3v.x, c3v.y, c3v.z, c3v.w};
        float Cs[NST] = {c4v.x, c4v.y, c4v.z, c4v.w, c5v.x, c5v.y, c5v.z, c5v.w,
                         c6v.x, c6v.y, c6v.z, c6v.w, c7v.x, c7v.y, c7v.z, c7v.w};
        float y = 0.f;
        #pragma unroll
        for (int n = 0; n < NST; ++n) {
            float denom = fmaf(-c0, An[n], 1.0f);
            float inv = __builtin_amdgcn_rcpf(denom);
            float a = (2.0f - denom) * inv;
            h[n] = fmaf(a, h[n], c1 * Bs[n] * inv);
            y = fmaf(Cs[n], h[n], y);
        }
        out[(size_t)l * DD + d] = fmaf(Dp, xv_c, y);
    }
}

extern "C" void kernel_launch(void* const* d_in, const int* in_sizes, int n_in,
                              void* d_out, int out_size, void* d_ws, size_t ws_size,
                              hipStream_t stream) {
    const float* x         = (const float*)d_in[0];
    const float* A_log     = (const float*)d_in[1];
    const float* D_param   = (const float*)d_in[2];
    const float* W_bc      = (const float*)d_in[3];
    const float* W_dt      = (const float*)d_in[4];
    const float* W_dtp     = (const float*)d_in[5];
    const float* b_dt      = (const float*)d_in[6];
    const float* rms_scale = (const float*)d_in[7];
    float* out = (float*)d_out;

    float* ws    = (float*)d_ws;
    float* delta = ws;                               // L*D        = 3,145,728
    float* bcbuf = delta + (size_t)LSEQ * DD;        // L*32       =   131,072
    float* Pbuf  = bcbuf + (size_t)LSEQ * 32;        // C*16*D     = 1,572,864
    float* Hbuf  = Pbuf + (size_t)NCH * NST * DD;    // C*16*D     = 1,572,864
    // total ws: ~25.7 MB

    k_proj<<<LSEQ / LTILE, 512, 0, stream>>>(x, W_bc, W_dt, W_dtp, b_dt,
                                             rms_scale, delta, bcbuf);
    k_scan1<<<dim3(DD / 256, NCH), 256, 0, stream>>>(x, delta, bcbuf, A_log,
                                                     Pbuf, Hbuf);
    k_scan2<<<(DD * NST) / 256, 256, 0, stream>>>(Pbuf, Hbuf);
    k_scan3<<<dim3(DD / 256, NCH), 256, 0, stream>>>(x, delta, bcbuf, A_log,
                                                     Pbuf, D_param, out);
}

// Round 5
// 118.194 us; speedup vs baseline: 1.1636x; 1.1636x over previous
//
#include <hip/hip_runtime.h>
#include <math.h>

#define LSEQ 4096
#define DD 768
#define NST 16
#define RNK 48
#define TCH 32
#define NCH (LSEQ / TCH)   // 128 chunks
#define LTILE 8
#define NH 8               // states per thread after 2-way split

__device__ __forceinline__ float softplus_f(float z) {
    return fmaxf(z, 0.0f) + log1pf(expf(-fabsf(z)));
}

__device__ __forceinline__ float soft_clamp_f(float v) {
    const float ctr = 5.00005f;
    const float hr  = 4.99995f;
    const float inv_hr = 1.0f / 4.99995f;
    return ctr + hr * tanhf((v - ctr) * inv_hr);
}

__device__ __forceinline__ float wave_sum(float v) {
    #pragma unroll
    for (int m = 32; m >= 1; m >>= 1) v += __shfl_xor(v, m, 64);
    return v;
}

// ---------------------------------------------------------------------------
// Kernel 1: per 8-timestep tile:
//   t = x@W_dt (8x48), bc = x@W_bc (8x32) -> global
//   delta = soft_clamp(rmsnorm(softplus(t@W_dtp + b_dt)) * rms_scale)
// v2: transposed x in LDS (b128 reads), single-sync RMS tail.
// ---------------------------------------------------------------------------
__global__ __launch_bounds__(512) void k_proj(
    const float* __restrict__ x, const float* __restrict__ W_bc,
    const float* __restrict__ W_dt, const float* __restrict__ W_dtp,
    const float* __restrict__ b_dt, const float* __restrict__ rms_scale,
    float* __restrict__ delta_out, float* __restrict__ bc_out)
{
    __shared__ __align__(16) float x_t[DD][LTILE];   // 24 KB, transposed
    __shared__ float t_lds[LTILE][RNK];              // 1.5 KB
    __shared__ float red[6][LTILE][80];              // 15 KB
    __shared__ float red2[8][LTILE];                 // per-wave RMS partials

    const int tid = threadIdx.x;
    const int l0  = blockIdx.x * LTILE;

    for (int i = tid; i < LTILE * DD; i += 512) {
        int li = i / DD, d = i % DD;
        x_t[d][li] = x[(size_t)(l0 + li) * DD + d];
    }
    __syncthreads();

    // ---- phase A: t (48 cols) + bc (32 cols), split-K over 6 partials ----
    {
        const int j = tid % 80, p = tid / 80;   // p in 0..6, p==6 idle
        if (p < 6) {
            float acc[LTILE];
            #pragma unroll
            for (int li = 0; li < LTILE; ++li) acc[li] = 0.f;
            const int dbase = p * 128;
            const int stride = (j < RNK) ? RNK : 32;
            const float* Wp = (j < RNK) ? (W_dt + (size_t)dbase * RNK + j)
                                        : (W_bc + (size_t)dbase * 32 + (j - RNK));
            for (int i = 0; i < 128; ++i) {
                int d = dbase + i;
                float4 xa = *(const float4*)&x_t[d][0];
                float4 xb = *(const float4*)&x_t[d][4];
                float w = *Wp; Wp += stride;
                acc[0] = fmaf(xa.x, w, acc[0]);
                acc[1] = fmaf(xa.y, w, acc[1]);
                acc[2] = fmaf(xa.z, w, acc[2]);
                acc[3] = fmaf(xa.w, w, acc[3]);
                acc[4] = fmaf(xb.x, w, acc[4]);
                acc[5] = fmaf(xb.y, w, acc[5]);
                acc[6] = fmaf(xb.z, w, acc[6]);
                acc[7] = fmaf(xb.w, w, acc[7]);
            }
            #pragma unroll
            for (int li = 0; li < LTILE; ++li) red[p][li][j] = acc[li];
        }
    }
    __syncthreads();
    for (int idx = tid; idx < LTILE * 80; idx += 512) {
        int li = idx / 80, jj = idx % 80;
        float s = red[0][li][jj] + red[1][li][jj] + red[2][li][jj]
                + red[3][li][jj] + red[4][li][jj] + red[5][li][jj];
        if (jj < RNK) t_lds[li][jj] = s;
        else          bc_out[(size_t)(l0 + li) * 32 + (jj - RNK)] = s;
    }
    __syncthreads();

    // ---- phase B: delta = soft_clamp(rmsnorm(softplus(t @ W_dtp + b))) ----
    const int d0 = tid;
    const int d1 = tid + 512;
    const bool has2 = (tid < 256);

    float z0[LTILE], z1[LTILE];
    float bb0 = b_dt[d0];
    float rs0 = rms_scale[d0];
    float bb1 = has2 ? b_dt[d1] : 0.f;
    float rs1 = has2 ? rms_scale[d1] : 0.f;
    #pragma unroll
    for (int li = 0; li < LTILE; ++li) { z0[li] = bb0; z1[li] = bb1; }

    for (int r = 0; r < RNK; ++r) {
        float w0 = W_dtp[r * DD + d0];
        float w1 = has2 ? W_dtp[r * DD + d1] : 0.f;
        #pragma unroll
        for (int li = 0; li < LTILE; ++li) {
            float t = t_lds[li][r];
            z0[li] = fmaf(t, w0, z0[li]);
            z1[li] = fmaf(t, w1, z1[li]);
        }
    }
    float sp0[LTILE], sp1[LTILE];
    #pragma unroll
    for (int li = 0; li < LTILE; ++li) {
        sp0[li] = softplus_f(z0[li]);
        sp1[li] = has2 ? softplus_f(z1[li]) : 0.f;
    }

    const int wid = tid >> 6, lane = tid & 63;
    #pragma unroll
    for (int li = 0; li < LTILE; ++li) {
        float ss = wave_sum(sp0[li] * sp0[li] + sp1[li] * sp1[li]);
        if (lane == 0) red2[wid][li] = ss;
    }
    __syncthreads();
    #pragma unroll
    for (int li = 0; li < LTILE; ++li) {
        float tot = 0.f;
        #pragma unroll
        for (int k = 0; k < 8; ++k) tot += red2[k][li];
        float inv = rsqrtf(tot * (1.0f / DD) + 1e-6f);
        delta_out[(size_t)(l0 + li) * DD + d0] = soft_clamp_f(sp0[li] * inv * rs0);
        if (has2)
            delta_out[(size_t)(l0 + li) * DD + d1] = soft_clamp_f(sp1[li] * inv * rs1);
    }
}

// ---------------------------------------------------------------------------
// Scan pass 1 (state-split): thread = (d, chunk, half of 8 states).
// Local scan h=0; store prod(a), h_end at [(c*16+n)*768+d].
// ---------------------------------------------------------------------------
__global__ __launch_bounds__(256) void k_scan1(
    const float* __restrict__ x, const float* __restrict__ delta,
    const float* __restrict__ bc, const float* __restrict__ A_log,
    float* __restrict__ Pbuf, float* __restrict__ Hbuf)
{
    const int d = blockIdx.x * 256 + threadIdx.x;
    const int c = blockIdx.y;
    const int half = blockIdx.z;          // 0 or 1
    const int l0 = c * TCH;

    float An[NH];
    {
        const float4* al = (const float4*)&A_log[d * NST + half * NH];
        float4 a0 = al[0], a1 = al[1];
        An[0] = -expf(a0.x); An[1] = -expf(a0.y);
        An[2] = -expf(a0.z); An[3] = -expf(a0.w);
        An[4] = -expf(a1.x); An[5] = -expf(a1.y);
        An[6] = -expf(a1.z); An[7] = -expf(a1.w);
    }
    float h[NH], Pp[NH];
    #pragma unroll
    for (int n = 0; n < NH; ++n) { h[n] = 0.f; Pp[n] = 1.f; }

    float xprev = (l0 == 0) ? 0.f : x[(size_t)(l0 - 1) * DD + d];
    float dv = delta[(size_t)l0 * DD + d];
    float xv = x[(size_t)l0 * DD + d];
    const float4* bcv = (const float4*)bc;
    const int boff = half * 2;            // B part: float4s {0,1} or {2,3}
    float4 b0 = bcv[l0 * 8 + boff], b1 = bcv[l0 * 8 + boff + 1];

    for (int ll = 0; ll < TCH; ++ll) {
        const int l = l0 + ll;
        const int lnx = (l + 1 < LSEQ) ? l + 1 : l;
        float dv_c = dv, xv_c = xv;
        float4 c0v = b0, c1v = b1;
        dv = delta[(size_t)lnx * DD + d];
        xv = x[(size_t)lnx * DD + d];
        b0 = bcv[lnx * 8 + boff]; b1 = bcv[lnx * 8 + boff + 1];

        float xin = 0.5f * (xv_c + xprev);
        xprev = xv_c;
        float c0 = 0.5f * dv_c;
        float c1 = sqrtf(dv_c) * xin;
        float Bs[NH] = {c0v.x, c0v.y, c0v.z, c0v.w, c1v.x, c1v.y, c1v.z, c1v.w};
        #pragma unroll
        for (int n = 0; n < NH; ++n) {
            float denom = fmaf(-c0, An[n], 1.0f);     // 1 - 0.5*delta*A
            float inv = __builtin_amdgcn_rcpf(denom);
            float a = (2.0f - denom) * inv;           // (1+half)/(1-half)
            Pp[n] *= a;
            h[n] = fmaf(a, h[n], c1 * Bs[n] * inv);
        }
    }
    #pragma unroll
    for (int n = 0; n < NH; ++n) {
        int idx = (c * NST + half * NH + n) * DD + d;
        Pbuf[idx] = Pp[n];
        Hbuf[idx] = h[n];
    }
}

// ---------------------------------------------------------------------------
// Scan pass 2: wave-parallel chunk-carry. One wave per (d,n) series.
// Lane k owns chunks 2k,2k+1; compose; Hillis-Steele over 64 lanes.
// Overwrites Pbuf with carry-IN h of each chunk.
// ---------------------------------------------------------------------------
__global__ __launch_bounds__(256) void k_scan2(
    float* __restrict__ Pbuf, const float* __restrict__ Hbuf)
{
    const int lane = threadIdx.x & 63;
    const int s = blockIdx.x * 4 + (threadIdx.x >> 6);  // series 0..12287
    const int d = s % DD;
    const int n = s / DD;

    const int c0 = 2 * lane;
    const int idx0 = (c0 * NST + n) * DD + d;
    const int idx1 = ((c0 + 1) * NST + n) * DD + d;
    float p0 = Pbuf[idx0], h0 = Hbuf[idx0];
    float p1 = Pbuf[idx1], h1 = Hbuf[idx1];

    // compose the lane's two chunks: (P,H) s.t. h_out = P*h_in + H
    float P = p1 * p0;
    float H = fmaf(p1, h0, h1);

    // inclusive wave scan with (Pl,Hl)∘(Pr,Hr) = (Pr*Pl, Pr*Hl + Hr)
    #pragma unroll
    for (int ofs = 1; ofs < 64; ofs <<= 1) {
        float Pp = __shfl_up(P, ofs, 64);
        float Hp = __shfl_up(H, ofs, 64);
        if (lane >= ofs) {
            H = fmaf(P, Hp, H);
            P = P * Pp;
        }
    }
    // exclusive H = carry-in h for this lane's first chunk
    float Hex = __shfl_up(H, 1, 64);
    if (lane == 0) Hex = 0.f;

    float carry0 = Hex;
    float carry1 = fmaf(p0, carry0, h0);
    Pbuf[idx0] = carry0;
    Pbuf[idx1] = carry1;
}

// ---------------------------------------------------------------------------
// Scan pass 3 (state-split, in-block y exchange): block = 128 d x 2 halves.
// Redo local scan seeded with carry-in; y = sum_n C*h + D*x.
// ---------------------------------------------------------------------------
__global__ __launch_bounds__(256) void k_scan3(
    const float* __restrict__ x, const float* __restrict__ delta,
    const float* __restrict__ bc, const float* __restrict__ A_log,
    const float* __restrict__ carryin, const float* __restrict__ D_param,
    float* __restrict__ out)
{
    __shared__ float ybuf[2][128];

    const int dloc = threadIdx.x & 127;
    const int half = threadIdx.x >> 7;    // 0 or 1
    const int d = blockIdx.x * 128 + dloc;
    const int c = blockIdx.y;
    const int l0 = c * TCH;

    float An[NH];
    {
        const float4* al = (const float4*)&A_log[d * NST + half * NH];
        float4 a0 = al[0], a1 = al[1];
        An[0] = -expf(a0.x); An[1] = -expf(a0.y);
        An[2] = -expf(a0.z); An[3] = -expf(a0.w);
        An[4] = -expf(a1.x); An[5] = -expf(a1.y);
        An[6] = -expf(a1.z); An[7] = -expf(a1.w);
    }
    float h[NH];
    #pragma unroll
    for (int n = 0; n < NH; ++n)
        h[n] = carryin[(c * NST + half * NH + n) * DD + d];
    const float Dp = D_param[d];

    float xprev = (l0 == 0) ? 0.f : x[(size_t)(l0 - 1) * DD + d];
    float dv = delta[(size_t)l0 * DD + d];
    float xv = x[(size_t)l0 * DD + d];
    const float4* bcv = (const float4*)bc;
    const int boff = half * 2;            // B float4s
    const int coff = 4 + half * 2;        // C float4s
    float4 b0 = bcv[l0 * 8 + boff], b1 = bcv[l0 * 8 + boff + 1];
    float4 g0 = bcv[l0 * 8 + coff], g1 = bcv[l0 * 8 + coff + 1];

    int buf = 0;
    for (int ll = 0; ll < TCH; ++ll) {
        const int l = l0 + ll;
        const int lnx = (l + 1 < LSEQ) ? l + 1 : l;
        float dv_c = dv, xv_c = xv;
        float4 c0v = b0, c1v = b1, g0v = g0, g1v = g1;
        dv = delta[(size_t)lnx * DD + d];
        xv = x[(size_t)lnx * DD + d];
        b0 = bcv[lnx * 8 + boff]; b1 = bcv[lnx * 8 + boff + 1];
        g0 = bcv[lnx * 8 + coff]; g1 = bcv[lnx * 8 + coff + 1];

        float xin = 0.5f * (xv_c + xprev);
        xprev = xv_c;
        float c0 = 0.5f * dv_c;
        float c1 = sqrtf(dv_c) * xin;
        float Bs[NH] = {c0v.x, c0v.y, c0v.z, c0v.w, c1v.x, c1v.y, c1v.z, c1v.w};
        float Cs[NH] = {g0v.x, g0v.y, g0v.z, g0v.w, g1v.x, g1v.y, g1v.z, g1v.w};
        float y = 0.f;
        #pragma unroll
        for (int n = 0; n < NH; ++n) {
            float denom = fmaf(-c0, An[n], 1.0f);
            float inv = __builtin_amdgcn_rcpf(denom);
            float a = (2.0f - denom) * inv;
            h[n] = fmaf(a, h[n], c1 * Bs[n] * inv);
            y = fmaf(Cs[n], h[n], y);
        }
        if (half == 1) ybuf[buf][dloc] = y;
        __syncthreads();
        if (half == 0)
            out[(size_t)l * DD + d] = fmaf(Dp, xv_c, y + ybuf[buf][dloc]);
        buf ^= 1;
    }
}

extern "C" void kernel_launch(void* const* d_in, const int* in_sizes, int n_in,
                              void* d_out, int out_size, void* d_ws, size_t ws_size,
                              hipStream_t stream) {
    const float* x         = (const float*)d_in[0];
    const float* A_log     = (const float*)d_in[1];
    const float* D_param   = (const float*)d_in[2];
    const float* W_bc      = (const float*)d_in[3];
    const float* W_dt      = (const float*)d_in[4];
    const float* W_dtp     = (const float*)d_in[5];
    const float* b_dt      = (const float*)d_in[6];
    const float* rms_scale = (const float*)d_in[7];
    float* out = (float*)d_out;

    float* ws    = (float*)d_ws;
    float* delta = ws;                               // L*D
    float* bcbuf = delta + (size_t)LSEQ * DD;        // L*32
    float* Pbuf  = bcbuf + (size_t)LSEQ * 32;        // NCH*16*D
    float* Hbuf  = Pbuf + (size_t)NCH * NST * DD;    // NCH*16*D
    // total ws: ~25.7 MB

    k_proj<<<LSEQ / LTILE, 512, 0, stream>>>(x, W_bc, W_dt, W_dtp, b_dt,
                                             rms_scale, delta, bcbuf);
    k_scan1<<<dim3(DD / 256, NCH, 2), 256, 0, stream>>>(x, delta, bcbuf, A_log,
                                                        Pbuf, Hbuf);
    k_scan2<<<(DD * NST) / 4, 256, 0, stream>>>(Pbuf, Hbuf);
    k_scan3<<<dim3(DD / 128, NCH), 256, 0, stream>>>(x, delta, bcbuf, A_log,
                                                     Pbuf, D_param, out);
}